// Round 2
// baseline (3286.143 us; speedup 1.0000x reference)
//
#include <hip/hip_runtime.h>
#include <stdint.h>

// Problem: B=64, T=128, F=1024, H=1024. x:[64,128,1024] f32, W:[2048,4096] f32, b:[4096] f32.
// out:[64,128,1024] f32.
#define BATCH 64
#define TSEQ  128
#define FDIM  1024
#define HDIM  1024
#define GDIM  4096              // 4H
#define MROWS 8192              // BATCH*TSEQ
#define NB    128               // persistent blocks in recurrent phase (co-resident on 256 CUs)

typedef short bf16x8 __attribute__((ext_vector_type(8)));   // 8 bf16 in 4 VGPRs
typedef float f32x4  __attribute__((ext_vector_type(4)));

__device__ __forceinline__ unsigned short f2bf(float f) {
    union { float f; uint32_t u; } v; v.f = f;
    uint32_t u = v.u;
    return (unsigned short)((u + 0x7FFFu + ((u >> 16) & 1u)) >> 16);  // RNE
}
__device__ __forceinline__ float bf2f(unsigned short h) {
    union { uint32_t u; float f; } v; v.u = ((uint32_t)h) << 16; return v.f;
}
__device__ __forceinline__ float sigmoidf_(float x) { return 1.f / (1.f + __expf(-x)); }
__device__ __forceinline__ float tanhf_(float x)    { return 2.f / (1.f + __expf(-2.f * x)) - 1.f; }

union SP { short s[8]; int4 v; };

// ---------------- init: zero h double-buffer + flags ----------------
__global__ void k_init(uint32_t* p, int nwords) {
    int i = blockIdx.x * blockDim.x + threadIdx.x;
    int s = gridDim.x * blockDim.x;
    for (; i < nwords; i += s) p[i] = 0;
}

// ---------------- W fp32 [2048][4096] -> WxT hi/lo bf16 [4096][1024], WhT bf16 [4096][1024] ----
__global__ void k_tw(const float* __restrict__ W,
                     unsigned short* __restrict__ wxth, unsigned short* __restrict__ wxtl,
                     unsigned short* __restrict__ wht) {
    __shared__ float tile[64 * 65];
    const int nb = blockIdx.x;      // 0..63  (n tiles)
    const int kb = blockIdx.y;      // 0..31  (k tiles over 2048)
    const int t  = threadIdx.x;
    const int col = t & 63, rg = t >> 6;
#pragma unroll
    for (int i = 0; i < 16; i++) {
        int row = rg * 16 + i;
        tile[row * 65 + col] = W[(size_t)(kb * 64 + row) * 4096 + nb * 64 + col];
    }
    __syncthreads();
    if (kb < 16) {
        const int kbase = kb * 64;
#pragma unroll
        for (int i = 0; i < 16; i++) {
            int rp = rg * 16 + i;                      // n index within tile
            float v = tile[col * 65 + rp];             // = W[kb*64+col][nb*64+rp]
            unsigned short h = f2bf(v);
            size_t idx = (size_t)(nb * 64 + rp) * 1024 + kbase + col;
            wxth[idx] = h;
            wxtl[idx] = f2bf(v - bf2f(h));
        }
    } else {
        const int kbase = (kb - 16) * 64;
#pragma unroll
        for (int i = 0; i < 16; i++) {
            int rp = rg * 16 + i;
            float v = tile[col * 65 + rp];
            wht[(size_t)(nb * 64 + rp) * 1024 + kbase + col] = f2bf(v);
        }
    }
}

// ---------------- GEMM1: xz_f32[8192][4096] = x[8192][1024] @ Wx, split-bf16 (3-MFMA) ---------
// 128x128 tile, BK=32, 256 thr (4 waves 2x2), each wave 4x4 tiles of 16x16x32 bf16 MFMA.
// x fp32 is split hi/lo in-kernel during staging; Wx hi/lo preconverted by k_tw.
__global__ __launch_bounds__(256) void k_gemm1(const float* __restrict__ Xf,
                                               const unsigned short* __restrict__ WxTh,
                                               const unsigned short* __restrict__ WxTl,
                                               float* __restrict__ xz) {
    __shared__ short Ash[128 * 40];   // stride 40 elems (80B) -> 2-way banks (free)
    __shared__ short Asl[128 * 40];
    __shared__ short Bsh[128 * 40];
    __shared__ short Bsl[128 * 40];
    const int n0 = blockIdx.x * 128;
    const int m0 = blockIdx.y * 128;
    const int t = threadIdx.x;
    const int wave = t >> 6, lane = t & 63;
    const int wm = wave >> 1, wn = wave & 1;
    const int q = lane >> 4, cl = lane & 15;
    const int row_a = t >> 2;            // 0..63
    const int kc = (t & 3) * 8;          // 8-elem chunk within the 32-elem k-slab

    f32x4 acc[4][4];
#pragma unroll
    for (int i = 0; i < 4; i++)
#pragma unroll
        for (int j = 0; j < 4; j++) acc[i][j] = (f32x4){0.f, 0.f, 0.f, 0.f};

    for (int kb = 0; kb < 32; kb++) {
        const int k0 = kb * 32;
        // A: two rows of 8 fp32 each (split to hi/lo below)
        float va0[8], va1[8];
        {
            const float* p0 = Xf + (size_t)(m0 + row_a) * 1024 + k0 + kc;
            const float* p1 = Xf + (size_t)(m0 + 64 + row_a) * 1024 + k0 + kc;
            *(float4*)(va0)     = *(const float4*)(p0);
            *(float4*)(va0 + 4) = *(const float4*)(p0 + 4);
            *(float4*)(va1)     = *(const float4*)(p1);
            *(float4*)(va1 + 4) = *(const float4*)(p1 + 4);
        }
        int4 bh0 = *(const int4*)(WxTh + (size_t)(n0 + row_a)      * 1024 + k0 + kc);
        int4 bh1 = *(const int4*)(WxTh + (size_t)(n0 + 64 + row_a) * 1024 + k0 + kc);
        int4 bl0 = *(const int4*)(WxTl + (size_t)(n0 + row_a)      * 1024 + k0 + kc);
        int4 bl1 = *(const int4*)(WxTl + (size_t)(n0 + 64 + row_a) * 1024 + k0 + kc);
        __syncthreads();
        {
            SP h0, l0, h1, l1;
#pragma unroll
            for (int i = 0; i < 8; i++) {
                unsigned short h = f2bf(va0[i]);
                h0.s[i] = (short)h; l0.s[i] = (short)f2bf(va0[i] - bf2f(h));
                unsigned short g = f2bf(va1[i]);
                h1.s[i] = (short)g; l1.s[i] = (short)f2bf(va1[i] - bf2f(g));
            }
            *(int4*)(Ash + row_a * 40 + kc)        = h0.v;
            *(int4*)(Asl + row_a * 40 + kc)        = l0.v;
            *(int4*)(Ash + (64 + row_a) * 40 + kc) = h1.v;
            *(int4*)(Asl + (64 + row_a) * 40 + kc) = l1.v;
        }
        *(int4*)(Bsh + row_a * 40 + kc)        = bh0;
        *(int4*)(Bsh + (64 + row_a) * 40 + kc) = bh1;
        *(int4*)(Bsl + row_a * 40 + kc)        = bl0;
        *(int4*)(Bsl + (64 + row_a) * 40 + kc) = bl1;
        __syncthreads();
        bf16x8 ah[4], al[4], bh[4], bl[4];
#pragma unroll
        for (int i = 0; i < 4; i++) {
            ah[i] = *(const bf16x8*)(Ash + (wm * 64 + i * 16 + cl) * 40 + q * 8);
            al[i] = *(const bf16x8*)(Asl + (wm * 64 + i * 16 + cl) * 40 + q * 8);
        }
#pragma unroll
        for (int j = 0; j < 4; j++) {
            bh[j] = *(const bf16x8*)(Bsh + (wn * 64 + j * 16 + cl) * 40 + q * 8);
            bl[j] = *(const bf16x8*)(Bsl + (wn * 64 + j * 16 + cl) * 40 + q * 8);
        }
#pragma unroll
        for (int i = 0; i < 4; i++)
#pragma unroll
            for (int j = 0; j < 4; j++) {
                acc[i][j] = __builtin_amdgcn_mfma_f32_16x16x32_bf16(ah[i], bh[j], acc[i][j], 0, 0, 0);
                acc[i][j] = __builtin_amdgcn_mfma_f32_16x16x32_bf16(al[i], bh[j], acc[i][j], 0, 0, 0);
                acc[i][j] = __builtin_amdgcn_mfma_f32_16x16x32_bf16(ah[i], bl[j], acc[i][j], 0, 0, 0);
            }
    }
    // epilogue: C/D layout col=lane&15, row=q*4+reg; write fp32
#pragma unroll
    for (int i = 0; i < 4; i++) {
#pragma unroll
        for (int j = 0; j < 4; j++) {
            int gm = m0 + wm * 64 + i * 16 + q * 4;
            int gn = n0 + wn * 64 + j * 16 + cl;
#pragma unroll
            for (int r = 0; r < 4; r++)
                xz[(size_t)(gm + r) * 4096 + gn] = acc[i][j][r];
        }
    }
}

// ---------------- persistent recurrent kernel ----------------
// NB=128 blocks x 256 thr. Block owns 8 h-cols (n0..n0+7) -> 32 gate cols, vcol order [i(8) j(8) | f(8) o(8)].
// Wh slice lives in LDS (exactly 64KB, XOR-swizzled 16B chunks). Per step: [64x1024]@[1024x32] MFMA.
__global__ __launch_bounds__(256) void k_rnn(const float* __restrict__ xz,
                                             const unsigned short* __restrict__ WhT,
                                             const float* __restrict__ bias,
                                             unsigned short* hbuf,       // 2 x [64][1024] bf16
                                             int* flags,                 // NB flags, stride 16 ints
                                             float* __restrict__ out) {
    __shared__ short Ws[32 * 1024];     // 64 KB
    const int t = threadIdx.x;
    const int blk = blockIdx.x;
    const int n0 = blk * 8;
    const int wave = t >> 6, lane = t & 63;
    const int q = lane >> 4, cl = lane & 15;
    const int m = wave * 16 + cl;       // A-fragment row (batch)

    // preload Wh slice into LDS: vcol = g*8+cc -> WhT row g*1024+n0+cc
    {
        const int vcol = t >> 3;            // 0..31
        const int part = t & 7;             // 0..7
        const int g = vcol >> 3, cc2 = vcol & 7, sw = vcol & 7;
        const unsigned short* src = WhT + (size_t)(g * 1024 + n0 + cc2) * 1024;
        short* dstrow = Ws + vcol * 1024;
#pragma unroll
        for (int i = 0; i < 16; i++) {
            int kch = part * 16 + i;        // 16B chunk id 0..127
            int4 v = *(const int4*)(src + kch * 8);
            *(int4*)(dstrow + ((kch ^ sw) * 8)) = v;
        }
    }
    const int cc = cl & 7;
    const bool act = (cl < 8);
    float bi = 0.f, bj = 0.f, bfv = 0.f, bo = 0.f;
    if (act) {
        bi  = bias[n0 + cc];
        bj  = bias[1024 + n0 + cc];
        bfv = bias[2048 + n0 + cc];
        bo  = bias[3072 + n0 + cc];
    }
    float c[4] = {0.f, 0.f, 0.f, 0.f};
    const int sw = cl & 7;
    __syncthreads();

    for (int tt = 0; tt < TSEQ; tt++) {
        const unsigned short* hprev = hbuf + (size_t)(tt & 1) * (64 * 1024);
        unsigned short* hnext = hbuf + (size_t)((tt + 1) & 1) * (64 * 1024);
        if (tt > 0) {
            if (t < NB) {
                while (__hip_atomic_load(&flags[t * 16], __ATOMIC_ACQUIRE,
                                         __HIP_MEMORY_SCOPE_AGENT) < tt) { }
            }
            __syncthreads();
            __threadfence();            // see other blocks' h writes
        }
        f32x4 acc0 = (f32x4){0.f, 0.f, 0.f, 0.f};
        f32x4 acc1 = (f32x4){0.f, 0.f, 0.f, 0.f};
        const unsigned short* arow = hprev + (size_t)m * 1024 + q * 8;
        bf16x8 a = *(const bf16x8*)(arow);
#pragma unroll 4
        for (int kb = 0; kb < 32; kb++) {
            bf16x8 acur = a;
            if (kb < 31) a = *(const bf16x8*)(arow + (kb + 1) * 32);
            const int ch = (kb * 4 + q) ^ sw;
            bf16x8 b0 = *(const bf16x8*)(Ws + cl * 1024 + ch * 8);
            bf16x8 b1 = *(const bf16x8*)(Ws + (16 + cl) * 1024 + ch * 8);
            acc0 = __builtin_amdgcn_mfma_f32_16x16x32_bf16(acur, b0, acc0, 0, 0, 0);
            acc1 = __builtin_amdgcn_mfma_f32_16x16x32_bf16(acur, b1, acc1, 0, 0, 0);
        }
        // gate math: lane (q,cl<8) row-group q*4+r, col cc; zj/zo live in lane^8
        float zi[4], zj[4], zf[4], zo[4];
#pragma unroll
        for (int r = 0; r < 4; r++) {
            float a0 = acc0[r], a1 = acc1[r];
            float a0x = __shfl_xor(a0, 8);
            float a1x = __shfl_xor(a1, 8);
            zi[r] = a0; zj[r] = a0x; zf[r] = a1; zo[r] = a1x;
        }
        if (act) {
#pragma unroll
            for (int r = 0; r < 4; r++) {
                int m2 = wave * 16 + q * 4 + r;            // batch row
                size_t xr = (size_t)(m2 * 128 + tt) * 4096;
                float vi = zi[r] + xz[xr + n0 + cc] + bi;
                float vj = zj[r] + xz[xr + 1024 + n0 + cc] + bj;
                float vf = zf[r] + xz[xr + 2048 + n0 + cc] + bfv + 1.0f;  // forget bias
                float vo = zo[r] + xz[xr + 3072 + n0 + cc] + bo;
                float cn = c[r] * sigmoidf_(vf) + sigmoidf_(vi) * tanhf_(vj);
                c[r] = cn;
                float h = tanhf_(cn) * sigmoidf_(vo);
                out[(size_t)(m2 * 128 + tt) * 1024 + n0 + cc] = h;
                hnext[(size_t)m2 * 1024 + n0 + cc] = f2bf(h);
            }
        }
        __syncthreads();
        if (t == 0) {
            __threadfence();
            __hip_atomic_store(&flags[blk * 16], tt + 1, __ATOMIC_RELEASE,
                               __HIP_MEMORY_SCOPE_AGENT);
        }
    }
}

// ---------------- launch ----------------
extern "C" void kernel_launch(void* const* d_in, const int* in_sizes, int n_in,
                              void* d_out, int out_size, void* d_ws, size_t ws_size,
                              hipStream_t stream) {
    const float* x = (const float*)d_in[0];
    const float* W = (const float*)d_in[1];
    const float* b = (const float*)d_in[2];
    float* out = (float*)d_out;
    char* ws = (char*)d_ws;

    // workspace layout (bytes):
    unsigned short* WXTH = (unsigned short*)(ws);                              // 8 MB
    unsigned short* WXTL = (unsigned short*)(ws + (size_t)8  * 1024 * 1024);   // 8 MB
    unsigned short* WHT  = (unsigned short*)(ws + (size_t)16 * 1024 * 1024);   // 8 MB
    float*          XZ   = (float*)         (ws + (size_t)24 * 1024 * 1024);   // 128 MB fp32
    unsigned short* HBUF = (unsigned short*)(ws + (size_t)152 * 1024 * 1024);  // 256 KB (2 bufs)
    int*            FLG  = (int*)(ws + (size_t)152 * 1024 * 1024 + 256 * 1024); // 8 KB

    // zero h double-buffer + flags ((262144 + 8192)/4 = 67584 words)
    k_init<<<256, 256, 0, stream>>>((uint32_t*)HBUF, 67584);
    dim3 gtw(64, 32);
    k_tw<<<gtw, 256, 0, stream>>>(W, WXTH, WXTL, WHT);
    dim3 gg(32, 64);   // x: N/128, y: M/128
    k_gemm1<<<gg, 256, 0, stream>>>(x, WXTH, WXTL, XZ);
    k_rnn<<<NB, 256, 0, stream>>>(XZ, WHT, b, HBUF, FLG, out);
}

// Round 3
// 1917.444 us; speedup vs baseline: 1.7138x; 1.7138x over previous
//
#include <hip/hip_runtime.h>
#include <stdint.h>

// Problem: B=64, T=128, F=1024, H=1024. x:[64,128,1024] f32, W:[2048,4096] f32, b:[4096] f32.
// out:[64,128,1024] f32.
#define BATCH 64
#define TSEQ  128
#define FDIM  1024
#define HDIM  1024
#define GDIM  4096              // 4H
#define MROWS 8192              // BATCH*TSEQ
#define NB    128               // persistent blocks in recurrent phase (co-resident on 256 CUs)

typedef short bf16x8 __attribute__((ext_vector_type(8)));   // 8 bf16 in 4 VGPRs
typedef float f32x4  __attribute__((ext_vector_type(4)));

__device__ __forceinline__ unsigned short f2bf(float f) {
    union { float f; uint32_t u; } v; v.f = f;
    uint32_t u = v.u;
    return (unsigned short)((u + 0x7FFFu + ((u >> 16) & 1u)) >> 16);  // RNE
}
__device__ __forceinline__ float bf2f(unsigned short h) {
    union { uint32_t u; float f; } v; v.u = ((uint32_t)h) << 16; return v.f;
}
__device__ __forceinline__ float sigmoidf_(float x) { return 1.f / (1.f + __expf(-x)); }
__device__ __forceinline__ float tanhf_(float x)    { return 2.f / (1.f + __expf(-2.f * x)) - 1.f; }

union SP { short s[8]; int4 v; };

// ---------------- init: zero h double-buffer + flags ----------------
__global__ void k_init(uint32_t* p, int nwords) {
    int i = blockIdx.x * blockDim.x + threadIdx.x;
    int s = gridDim.x * blockDim.x;
    for (; i < nwords; i += s) p[i] = 0;
}

// ---------------- W fp32 [2048][4096] -> WxT hi/lo bf16 [4096][1024], WhT bf16 [4096][1024] ----
__global__ void k_tw(const float* __restrict__ W,
                     unsigned short* __restrict__ wxth, unsigned short* __restrict__ wxtl,
                     unsigned short* __restrict__ wht) {
    __shared__ float tile[64 * 65];
    const int nb = blockIdx.x;      // 0..63  (n tiles)
    const int kb = blockIdx.y;      // 0..31  (k tiles over 2048)
    const int t  = threadIdx.x;
    const int col = t & 63, rg = t >> 6;
#pragma unroll
    for (int i = 0; i < 16; i++) {
        int row = rg * 16 + i;
        tile[row * 65 + col] = W[(size_t)(kb * 64 + row) * 4096 + nb * 64 + col];
    }
    __syncthreads();
    if (kb < 16) {
        const int kbase = kb * 64;
#pragma unroll
        for (int i = 0; i < 16; i++) {
            int rp = rg * 16 + i;                      // n index within tile
            float v = tile[col * 65 + rp];             // = W[kb*64+col][nb*64+rp]
            unsigned short h = f2bf(v);
            size_t idx = (size_t)(nb * 64 + rp) * 1024 + kbase + col;
            wxth[idx] = h;
            wxtl[idx] = f2bf(v - bf2f(h));
        }
    } else {
        const int kbase = (kb - 16) * 64;
#pragma unroll
        for (int i = 0; i < 16; i++) {
            int rp = rg * 16 + i;
            float v = tile[col * 65 + rp];
            wht[(size_t)(nb * 64 + rp) * 1024 + kbase + col] = f2bf(v);
        }
    }
}

// ---------------- GEMM1: xz_f32[8192][4096] = x[8192][1024] @ Wx, split-bf16 (3-MFMA) ---------
__global__ __launch_bounds__(256) void k_gemm1(const float* __restrict__ Xf,
                                               const unsigned short* __restrict__ WxTh,
                                               const unsigned short* __restrict__ WxTl,
                                               float* __restrict__ xz) {
    __shared__ short Ash[128 * 40];   // stride 40 elems (80B) -> 2-way banks (free)
    __shared__ short Asl[128 * 40];
    __shared__ short Bsh[128 * 40];
    __shared__ short Bsl[128 * 40];
    const int n0 = blockIdx.x * 128;
    const int m0 = blockIdx.y * 128;
    const int t = threadIdx.x;
    const int wave = t >> 6, lane = t & 63;
    const int wm = wave >> 1, wn = wave & 1;
    const int q = lane >> 4, cl = lane & 15;
    const int row_a = t >> 2;            // 0..63
    const int kc = (t & 3) * 8;          // 8-elem chunk within the 32-elem k-slab

    f32x4 acc[4][4];
#pragma unroll
    for (int i = 0; i < 4; i++)
#pragma unroll
        for (int j = 0; j < 4; j++) acc[i][j] = (f32x4){0.f, 0.f, 0.f, 0.f};

    for (int kb = 0; kb < 32; kb++) {
        const int k0 = kb * 32;
        float va0[8], va1[8];
        {
            const float* p0 = Xf + (size_t)(m0 + row_a) * 1024 + k0 + kc;
            const float* p1 = Xf + (size_t)(m0 + 64 + row_a) * 1024 + k0 + kc;
            *(float4*)(va0)     = *(const float4*)(p0);
            *(float4*)(va0 + 4) = *(const float4*)(p0 + 4);
            *(float4*)(va1)     = *(const float4*)(p1);
            *(float4*)(va1 + 4) = *(const float4*)(p1 + 4);
        }
        int4 bh0 = *(const int4*)(WxTh + (size_t)(n0 + row_a)      * 1024 + k0 + kc);
        int4 bh1 = *(const int4*)(WxTh + (size_t)(n0 + 64 + row_a) * 1024 + k0 + kc);
        int4 bl0 = *(const int4*)(WxTl + (size_t)(n0 + row_a)      * 1024 + k0 + kc);
        int4 bl1 = *(const int4*)(WxTl + (size_t)(n0 + 64 + row_a) * 1024 + k0 + kc);
        __syncthreads();
        {
            SP h0, l0, h1, l1;
#pragma unroll
            for (int i = 0; i < 8; i++) {
                unsigned short h = f2bf(va0[i]);
                h0.s[i] = (short)h; l0.s[i] = (short)f2bf(va0[i] - bf2f(h));
                unsigned short g = f2bf(va1[i]);
                h1.s[i] = (short)g; l1.s[i] = (short)f2bf(va1[i] - bf2f(g));
            }
            *(int4*)(Ash + row_a * 40 + kc)        = h0.v;
            *(int4*)(Asl + row_a * 40 + kc)        = l0.v;
            *(int4*)(Ash + (64 + row_a) * 40 + kc) = h1.v;
            *(int4*)(Asl + (64 + row_a) * 40 + kc) = l1.v;
        }
        *(int4*)(Bsh + row_a * 40 + kc)        = bh0;
        *(int4*)(Bsh + (64 + row_a) * 40 + kc) = bh1;
        *(int4*)(Bsl + row_a * 40 + kc)        = bl0;
        *(int4*)(Bsl + (64 + row_a) * 40 + kc) = bl1;
        __syncthreads();
        bf16x8 ah[4], al[4], bh[4], bl[4];
#pragma unroll
        for (int i = 0; i < 4; i++) {
            ah[i] = *(const bf16x8*)(Ash + (wm * 64 + i * 16 + cl) * 40 + q * 8);
            al[i] = *(const bf16x8*)(Asl + (wm * 64 + i * 16 + cl) * 40 + q * 8);
        }
#pragma unroll
        for (int j = 0; j < 4; j++) {
            bh[j] = *(const bf16x8*)(Bsh + (wn * 64 + j * 16 + cl) * 40 + q * 8);
            bl[j] = *(const bf16x8*)(Bsl + (wn * 64 + j * 16 + cl) * 40 + q * 8);
        }
#pragma unroll
        for (int i = 0; i < 4; i++)
#pragma unroll
            for (int j = 0; j < 4; j++) {
                acc[i][j] = __builtin_amdgcn_mfma_f32_16x16x32_bf16(ah[i], bh[j], acc[i][j], 0, 0, 0);
                acc[i][j] = __builtin_amdgcn_mfma_f32_16x16x32_bf16(al[i], bh[j], acc[i][j], 0, 0, 0);
                acc[i][j] = __builtin_amdgcn_mfma_f32_16x16x32_bf16(ah[i], bl[j], acc[i][j], 0, 0, 0);
            }
    }
    // epilogue: C/D layout col=lane&15, row=q*4+reg; write fp32
#pragma unroll
    for (int i = 0; i < 4; i++) {
#pragma unroll
        for (int j = 0; j < 4; j++) {
            int gm = m0 + wm * 64 + i * 16 + q * 4;
            int gn = n0 + wn * 64 + j * 16 + cl;
#pragma unroll
            for (int r = 0; r < 4; r++)
                xz[(size_t)(gm + r) * 4096 + gn] = acc[i][j][r];
        }
    }
}

// ---------------- persistent recurrent kernel ----------------
// NB=128 blocks x 256 thr. Block owns 8 h-cols -> 32 gate cols [i(8) j(8) | f(8) o(8)].
// Wh slice in LDS (64KB, XOR-swizzled). Per step: [64x1024]@[1024x32] MFMA.
// Sync: RELAXED flag polls (sc0 sc1 loads, no cache inv) + ONE acquire fence per step;
//       release fence + relaxed flag store by t0. This is the R2 fix: acquire-per-poll
//       emitted buffer_inv per iteration -> 23 us/step L2-invalidate storm.
__global__ __launch_bounds__(256) void k_rnn(const float* __restrict__ xz,
                                             const unsigned short* __restrict__ WhT,
                                             const float* __restrict__ bias,
                                             unsigned short* hbuf,       // 2 x [64][1024] bf16
                                             int* flags,                 // NB flags, stride 16 ints
                                             float* __restrict__ out) {
    __shared__ short Ws[32 * 1024];     // 64 KB
    const int t = threadIdx.x;
    const int blk = blockIdx.x;
    const int n0 = blk * 8;
    const int wave = t >> 6, lane = t & 63;
    const int q = lane >> 4, cl = lane & 15;
    const int m = wave * 16 + cl;       // A-fragment row (batch)

    // preload Wh slice into LDS: vcol = g*8+cc -> WhT row g*1024+n0+cc
    {
        const int vcol = t >> 3;            // 0..31
        const int part = t & 7;             // 0..7
        const int g = vcol >> 3, cc2 = vcol & 7, swl = vcol & 7;
        const unsigned short* src = WhT + (size_t)(g * 1024 + n0 + cc2) * 1024;
        short* dstrow = Ws + vcol * 1024;
#pragma unroll
        for (int i = 0; i < 16; i++) {
            int kch = part * 16 + i;        // 16B chunk id 0..127
            int4 v = *(const int4*)(src + kch * 8);
            *(int4*)(dstrow + ((kch ^ swl) * 8)) = v;
        }
    }
    const int cc = cl & 7;
    const bool act = (cl < 8);
    float bi = 0.f, bj = 0.f, bfv = 0.f, bo = 0.f;
    if (act) {
        bi  = bias[n0 + cc];
        bj  = bias[1024 + n0 + cc];
        bfv = bias[2048 + n0 + cc];
        bo  = bias[3072 + n0 + cc];
    }
    float c[4] = {0.f, 0.f, 0.f, 0.f};
    const int sw = cl & 7;
    __syncthreads();

    for (int tt = 0; tt < TSEQ; tt++) {
        // prefetch xz for this step (independent of other blocks' h) — hides latency under spin
        float pxi[4], pxj[4], pxf[4], pxo[4];
        if (act) {
#pragma unroll
            for (int r = 0; r < 4; r++) {
                int m2 = wave * 16 + q * 4 + r;
                const float* xp = xz + (size_t)(m2 * 128 + tt) * 4096 + n0 + cc;
                pxi[r] = xp[0];
                pxj[r] = xp[1024];
                pxf[r] = xp[2048];
                pxo[r] = xp[3072];
            }
        }
        const unsigned short* hprev = hbuf + (size_t)(tt & 1) * (64 * 1024);
        unsigned short* hnext = hbuf + (size_t)((tt + 1) & 1) * (64 * 1024);
        if (tt > 0) {
            if (t < NB) {
                // RELAXED poll: plain coherent load from L3, no per-iteration cache inv
                while (__hip_atomic_load(&flags[t * 16], __ATOMIC_RELAXED,
                                         __HIP_MEMORY_SCOPE_AGENT) < tt) { }
            }
            __syncthreads();
            __builtin_amdgcn_fence(__ATOMIC_ACQUIRE, "agent");   // one inv per step
        }
        f32x4 acc0a = (f32x4){0.f, 0.f, 0.f, 0.f};
        f32x4 acc0b = (f32x4){0.f, 0.f, 0.f, 0.f};
        f32x4 acc1a = (f32x4){0.f, 0.f, 0.f, 0.f};
        f32x4 acc1b = (f32x4){0.f, 0.f, 0.f, 0.f};
        const unsigned short* arow = hprev + (size_t)m * 1024 + q * 8;
        bf16x8 a = *(const bf16x8*)(arow);
#pragma unroll 4
        for (int kb = 0; kb < 32; kb += 2) {
            bf16x8 a0c = a;
            bf16x8 a1c = *(const bf16x8*)(arow + (kb + 1) * 32);
            if (kb < 30) a = *(const bf16x8*)(arow + (kb + 2) * 32);
            const int ch0 = (kb * 4 + q) ^ sw;
            const int ch1 = ((kb + 1) * 4 + q) ^ sw;
            bf16x8 b00 = *(const bf16x8*)(Ws + cl * 1024 + ch0 * 8);
            bf16x8 b10 = *(const bf16x8*)(Ws + (16 + cl) * 1024 + ch0 * 8);
            bf16x8 b01 = *(const bf16x8*)(Ws + cl * 1024 + ch1 * 8);
            bf16x8 b11 = *(const bf16x8*)(Ws + (16 + cl) * 1024 + ch1 * 8);
            acc0a = __builtin_amdgcn_mfma_f32_16x16x32_bf16(a0c, b00, acc0a, 0, 0, 0);
            acc1a = __builtin_amdgcn_mfma_f32_16x16x32_bf16(a0c, b10, acc1a, 0, 0, 0);
            acc0b = __builtin_amdgcn_mfma_f32_16x16x32_bf16(a1c, b01, acc0b, 0, 0, 0);
            acc1b = __builtin_amdgcn_mfma_f32_16x16x32_bf16(a1c, b11, acc1b, 0, 0, 0);
        }
        f32x4 acc0 = acc0a + acc0b;
        f32x4 acc1 = acc1a + acc1b;
        // gate math: lane (q,cl<8) row-group q*4+r, col cc; zj/zo live in lane^8
        float zi[4], zj[4], zf[4], zo[4];
#pragma unroll
        for (int r = 0; r < 4; r++) {
            float a0 = acc0[r], a1 = acc1[r];
            float a0x = __shfl_xor(a0, 8);
            float a1x = __shfl_xor(a1, 8);
            zi[r] = a0; zj[r] = a0x; zf[r] = a1; zo[r] = a1x;
        }
        if (act) {
#pragma unroll
            for (int r = 0; r < 4; r++) {
                int m2 = wave * 16 + q * 4 + r;            // batch row
                float vi = zi[r] + pxi[r] + bi;
                float vj = zj[r] + pxj[r] + bj;
                float vf = zf[r] + pxf[r] + bfv + 1.0f;    // forget bias
                float vo = zo[r] + pxo[r] + bo;
                float cn = c[r] * sigmoidf_(vf) + sigmoidf_(vi) * tanhf_(vj);
                c[r] = cn;
                float h = tanhf_(cn) * sigmoidf_(vo);
                out[(size_t)(m2 * 128 + tt) * 1024 + n0 + cc] = h;
                hnext[(size_t)m2 * 1024 + n0 + cc] = f2bf(h);
            }
        }
        __syncthreads();   // drains vmcnt: all h stores in L2 before release
        if (t == 0) {
            __builtin_amdgcn_fence(__ATOMIC_RELEASE, "agent");   // one wbl2 per step
            __hip_atomic_store(&flags[blk * 16], tt + 1, __ATOMIC_RELAXED,
                               __HIP_MEMORY_SCOPE_AGENT);
        }
    }
}

// ---------------- launch ----------------
extern "C" void kernel_launch(void* const* d_in, const int* in_sizes, int n_in,
                              void* d_out, int out_size, void* d_ws, size_t ws_size,
                              hipStream_t stream) {
    const float* x = (const float*)d_in[0];
    const float* W = (const float*)d_in[1];
    const float* b = (const float*)d_in[2];
    float* out = (float*)d_out;
    char* ws = (char*)d_ws;

    // workspace layout (bytes):
    unsigned short* WXTH = (unsigned short*)(ws);                              // 8 MB
    unsigned short* WXTL = (unsigned short*)(ws + (size_t)8  * 1024 * 1024);   // 8 MB
    unsigned short* WHT  = (unsigned short*)(ws + (size_t)16 * 1024 * 1024);   // 8 MB
    float*          XZ   = (float*)         (ws + (size_t)24 * 1024 * 1024);   // 128 MB fp32
    unsigned short* HBUF = (unsigned short*)(ws + (size_t)152 * 1024 * 1024);  // 256 KB (2 bufs)
    int*            FLG  = (int*)(ws + (size_t)152 * 1024 * 1024 + 256 * 1024); // 8 KB

    // zero h double-buffer + flags ((262144 + 8192)/4 = 67584 words)
    k_init<<<256, 256, 0, stream>>>((uint32_t*)HBUF, 67584);
    dim3 gtw(64, 32);
    k_tw<<<gtw, 256, 0, stream>>>(W, WXTH, WXTL, WHT);
    dim3 gg(32, 64);   // x: N/128, y: M/128
    k_gemm1<<<gg, 256, 0, stream>>>(x, WXTH, WXTL, XZ);
    k_rnn<<<NB, 256, 0, stream>>>(XZ, WHT, b, HBUF, FLG, out);
}

// Round 4
// 1653.450 us; speedup vs baseline: 1.9874x; 1.1597x over previous
//
#include <hip/hip_runtime.h>
#include <stdint.h>

// Problem: B=64, T=128, F=1024, H=1024. x:[64,128,1024] f32, W:[2048,4096] f32, b:[4096] f32.
// out:[64,128,1024] f32.
#define BATCH 64
#define TSEQ  128
#define FDIM  1024
#define HDIM  1024
#define GDIM  4096              // 4H
#define MROWS 8192              // BATCH*TSEQ
#define NB    128               // persistent blocks in recurrent phase (co-resident on 256 CUs)

typedef short bf16x8 __attribute__((ext_vector_type(8)));   // 8 bf16 in 4 VGPRs
typedef float f32x4  __attribute__((ext_vector_type(4)));

__device__ __forceinline__ unsigned short f2bf(float f) {
    union { float f; uint32_t u; } v; v.f = f;
    uint32_t u = v.u;
    return (unsigned short)((u + 0x7FFFu + ((u >> 16) & 1u)) >> 16);  // RNE
}
__device__ __forceinline__ float bf2f(unsigned short h) {
    union { uint32_t u; float f; } v; v.u = ((uint32_t)h) << 16; return v.f;
}
__device__ __forceinline__ float sigmoidf_(float x) { return 1.f / (1.f + __expf(-x)); }
__device__ __forceinline__ float tanhf_(float x)    { return 2.f / (1.f + __expf(-2.f * x)) - 1.f; }

union SP { short s[8]; int4 v; };

// L3-coherent (L1/L2-bypass) accessors — the fence-free h exchange path.
__device__ __forceinline__ unsigned long long ld64cc(const void* p) {
    return __hip_atomic_load((const unsigned long long*)p, __ATOMIC_RELAXED,
                             __HIP_MEMORY_SCOPE_AGENT);
}
__device__ __forceinline__ void st16cc(void* p, uint32_t v) {
    asm volatile("global_store_short %0, %1, off sc0 sc1" :: "v"(p), "v"(v) : "memory");
}

// ---------------- init: zero h double-buffer + step counters ----------------
__global__ void k_init(uint32_t* p, int nwords) {
    int i = blockIdx.x * blockDim.x + threadIdx.x;
    int s = gridDim.x * blockDim.x;
    for (; i < nwords; i += s) p[i] = 0;
}

// ---------------- W fp32 [2048][4096] -> WxT hi/lo bf16 [4096][1024], WhT bf16 [4096][1024] ----
__global__ void k_tw(const float* __restrict__ W,
                     unsigned short* __restrict__ wxth, unsigned short* __restrict__ wxtl,
                     unsigned short* __restrict__ wht) {
    __shared__ float tile[64 * 65];
    const int nb = blockIdx.x;      // 0..63  (n tiles)
    const int kb = blockIdx.y;      // 0..31  (k tiles over 2048)
    const int t  = threadIdx.x;
    const int col = t & 63, rg = t >> 6;
#pragma unroll
    for (int i = 0; i < 16; i++) {
        int row = rg * 16 + i;
        tile[row * 65 + col] = W[(size_t)(kb * 64 + row) * 4096 + nb * 64 + col];
    }
    __syncthreads();
    if (kb < 16) {
        const int kbase = kb * 64;
#pragma unroll
        for (int i = 0; i < 16; i++) {
            int rp = rg * 16 + i;                      // n index within tile
            float v = tile[col * 65 + rp];             // = W[kb*64+col][nb*64+rp]
            unsigned short h = f2bf(v);
            size_t idx = (size_t)(nb * 64 + rp) * 1024 + kbase + col;
            wxth[idx] = h;
            wxtl[idx] = f2bf(v - bf2f(h));
        }
    } else {
        const int kbase = (kb - 16) * 64;
#pragma unroll
        for (int i = 0; i < 16; i++) {
            int rp = rg * 16 + i;
            float v = tile[col * 65 + rp];
            wht[(size_t)(nb * 64 + rp) * 1024 + kbase + col] = f2bf(v);
        }
    }
}

// ---------------- GEMM1: xz_f32[8192][4096] = x[8192][1024] @ Wx, split-bf16 (3-MFMA) ---------
__global__ __launch_bounds__(256) void k_gemm1(const float* __restrict__ Xf,
                                               const unsigned short* __restrict__ WxTh,
                                               const unsigned short* __restrict__ WxTl,
                                               float* __restrict__ xz) {
    __shared__ short Ash[128 * 40];   // stride 40 elems (80B) -> 2-way banks (free)
    __shared__ short Asl[128 * 40];
    __shared__ short Bsh[128 * 40];
    __shared__ short Bsl[128 * 40];
    const int n0 = blockIdx.x * 128;
    const int m0 = blockIdx.y * 128;
    const int t = threadIdx.x;
    const int wave = t >> 6, lane = t & 63;
    const int wm = wave >> 1, wn = wave & 1;
    const int q = lane >> 4, cl = lane & 15;
    const int row_a = t >> 2;            // 0..63
    const int kc = (t & 3) * 8;          // 8-elem chunk within the 32-elem k-slab

    f32x4 acc[4][4];
#pragma unroll
    for (int i = 0; i < 4; i++)
#pragma unroll
        for (int j = 0; j < 4; j++) acc[i][j] = (f32x4){0.f, 0.f, 0.f, 0.f};

    for (int kb = 0; kb < 32; kb++) {
        const int k0 = kb * 32;
        float va0[8], va1[8];
        {
            const float* p0 = Xf + (size_t)(m0 + row_a) * 1024 + k0 + kc;
            const float* p1 = Xf + (size_t)(m0 + 64 + row_a) * 1024 + k0 + kc;
            *(float4*)(va0)     = *(const float4*)(p0);
            *(float4*)(va0 + 4) = *(const float4*)(p0 + 4);
            *(float4*)(va1)     = *(const float4*)(p1);
            *(float4*)(va1 + 4) = *(const float4*)(p1 + 4);
        }
        int4 bh0 = *(const int4*)(WxTh + (size_t)(n0 + row_a)      * 1024 + k0 + kc);
        int4 bh1 = *(const int4*)(WxTh + (size_t)(n0 + 64 + row_a) * 1024 + k0 + kc);
        int4 bl0 = *(const int4*)(WxTl + (size_t)(n0 + row_a)      * 1024 + k0 + kc);
        int4 bl1 = *(const int4*)(WxTl + (size_t)(n0 + 64 + row_a) * 1024 + k0 + kc);
        __syncthreads();
        {
            SP h0, l0, h1, l1;
#pragma unroll
            for (int i = 0; i < 8; i++) {
                unsigned short h = f2bf(va0[i]);
                h0.s[i] = (short)h; l0.s[i] = (short)f2bf(va0[i] - bf2f(h));
                unsigned short g = f2bf(va1[i]);
                h1.s[i] = (short)g; l1.s[i] = (short)f2bf(va1[i] - bf2f(g));
            }
            *(int4*)(Ash + row_a * 40 + kc)        = h0.v;
            *(int4*)(Asl + row_a * 40 + kc)        = l0.v;
            *(int4*)(Ash + (64 + row_a) * 40 + kc) = h1.v;
            *(int4*)(Asl + (64 + row_a) * 40 + kc) = l1.v;
        }
        *(int4*)(Bsh + row_a * 40 + kc)        = bh0;
        *(int4*)(Bsh + (64 + row_a) * 40 + kc) = bh1;
        *(int4*)(Bsl + row_a * 40 + kc)        = bl0;
        *(int4*)(Bsl + (64 + row_a) * 40 + kc) = bl1;
        __syncthreads();
        bf16x8 ah[4], al[4], bh[4], bl[4];
#pragma unroll
        for (int i = 0; i < 4; i++) {
            ah[i] = *(const bf16x8*)(Ash + (wm * 64 + i * 16 + cl) * 40 + q * 8);
            al[i] = *(const bf16x8*)(Asl + (wm * 64 + i * 16 + cl) * 40 + q * 8);
        }
#pragma unroll
        for (int j = 0; j < 4; j++) {
            bh[j] = *(const bf16x8*)(Bsh + (wn * 64 + j * 16 + cl) * 40 + q * 8);
            bl[j] = *(const bf16x8*)(Bsl + (wn * 64 + j * 16 + cl) * 40 + q * 8);
        }
#pragma unroll
        for (int i = 0; i < 4; i++)
#pragma unroll
            for (int j = 0; j < 4; j++) {
                acc[i][j] = __builtin_amdgcn_mfma_f32_16x16x32_bf16(ah[i], bh[j], acc[i][j], 0, 0, 0);
                acc[i][j] = __builtin_amdgcn_mfma_f32_16x16x32_bf16(al[i], bh[j], acc[i][j], 0, 0, 0);
                acc[i][j] = __builtin_amdgcn_mfma_f32_16x16x32_bf16(ah[i], bl[j], acc[i][j], 0, 0, 0);
            }
    }
    // epilogue: C/D layout col=lane&15, row=q*4+reg; write fp32
#pragma unroll
    for (int i = 0; i < 4; i++) {
#pragma unroll
        for (int j = 0; j < 4; j++) {
            int gm = m0 + wm * 64 + i * 16 + q * 4;
            int gn = n0 + wn * 64 + j * 16 + cl;
#pragma unroll
            for (int r = 0; r < 4; r++)
                xz[(size_t)(gm + r) * 4096 + gn] = acc[i][j][r];
        }
    }
}

// ---------------- persistent recurrent kernel ----------------
// NB=128 blocks x 256 thr. Block owns 8 h-cols -> 32 gate cols [i(8) j(8) | f(8) o(8)].
// Wh slice in LDS (64KB, XOR-swizzled). Per step: [64x1024]@[1024x32] MFMA.
// Sync (R4): ZERO cache-maintenance. h exchanged through L3 directly:
//   stores  = global_store_short sc0 sc1 (bypass L1/L2, land at L3)
//   loads   = agent-relaxed atomic u64   (bypass L1/L2, read L3)
//   signal  = one fetch_add per block/step on cnt[tt]; consumers poll cnt[tt-1]==NB.
// __syncthreads() drains vmcnt(0), so the add is ordered after h stores ACK at L3
// -> release/acquire without buffer_wbl2/buffer_inv (the 12 us/step R3 cost).
__global__ __launch_bounds__(256) void k_rnn(const float* __restrict__ xz,
                                             const unsigned short* __restrict__ WhT,
                                             const float* __restrict__ bias,
                                             unsigned short* hbuf,       // 2 x [64][1024] bf16
                                             int* cnt,                   // TSEQ step counters
                                             float* __restrict__ out) {
    __shared__ short Ws[32 * 1024];     // 64 KB
    const int t = threadIdx.x;
    const int blk = blockIdx.x;
    const int n0 = blk * 8;
    const int wave = t >> 6, lane = t & 63;
    const int q = lane >> 4, cl = lane & 15;
    const int m = wave * 16 + cl;       // A-fragment row (batch)

    // preload Wh slice into LDS: vcol = g*8+cc -> WhT row g*1024+n0+cc
    {
        const int vcol = t >> 3;            // 0..31
        const int part = t & 7;             // 0..7
        const int g = vcol >> 3, cc2 = vcol & 7, swl = vcol & 7;
        const unsigned short* src = WhT + (size_t)(g * 1024 + n0 + cc2) * 1024;
        short* dstrow = Ws + vcol * 1024;
#pragma unroll
        for (int i = 0; i < 16; i++) {
            int kch = part * 16 + i;        // 16B chunk id 0..127
            int4 v = *(const int4*)(src + kch * 8);
            *(int4*)(dstrow + ((kch ^ swl) * 8)) = v;
        }
    }
    const int cc = cl & 7;
    const bool act = (cl < 8);
    float bi = 0.f, bj = 0.f, bfv = 0.f, bo = 0.f;
    if (act) {
        bi  = bias[n0 + cc];
        bj  = bias[1024 + n0 + cc];
        bfv = bias[2048 + n0 + cc];
        bo  = bias[3072 + n0 + cc];
    }
    float c[4] = {0.f, 0.f, 0.f, 0.f};
    const int sw = cl & 7;
    union U { unsigned long long u[2]; bf16x8 v; };
    __syncthreads();

    for (int tt = 0; tt < TSEQ; tt++) {
        // prefetch xz for this step (independent of other blocks' h) — hides latency under spin
        float pxi[4], pxj[4], pxf[4], pxo[4];
        if (act) {
#pragma unroll
            for (int r = 0; r < 4; r++) {
                int m2 = wave * 16 + q * 4 + r;
                const float* xp = xz + (size_t)(m2 * 128 + tt) * 4096 + n0 + cc;
                pxi[r] = xp[0];
                pxj[r] = xp[1024];
                pxf[r] = xp[2048];
                pxo[r] = xp[3072];
            }
        }
        const char* hprev = (const char*)hbuf + (size_t)(tt & 1) * (64 * 1024 * 2);
        char*       hnext = (char*)hbuf + (size_t)((tt + 1) & 1) * (64 * 1024 * 2);
        if (tt > 0) {
            if (t == 0) {
                while (__hip_atomic_load(&cnt[tt - 1], __ATOMIC_RELAXED,
                                         __HIP_MEMORY_SCOPE_AGENT) < NB) { }
            }
            __syncthreads();
        }
        f32x4 acc0a = (f32x4){0.f, 0.f, 0.f, 0.f};
        f32x4 acc0b = (f32x4){0.f, 0.f, 0.f, 0.f};
        f32x4 acc1a = (f32x4){0.f, 0.f, 0.f, 0.f};
        f32x4 acc1b = (f32x4){0.f, 0.f, 0.f, 0.f};
        const char* ab = hprev + (size_t)m * 2048 + q * 16;   // byte addr of lane's A row chunk
#pragma unroll 4
        for (int kb = 0; kb < 32; kb += 2) {
            U a0, a1;
            a0.u[0] = ld64cc(ab + kb * 64);
            a0.u[1] = ld64cc(ab + kb * 64 + 8);
            a1.u[0] = ld64cc(ab + kb * 64 + 64);
            a1.u[1] = ld64cc(ab + kb * 64 + 72);
            const int ch0 = (kb * 4 + q) ^ sw;
            const int ch1 = ((kb + 1) * 4 + q) ^ sw;
            bf16x8 b00 = *(const bf16x8*)(Ws + cl * 1024 + ch0 * 8);
            bf16x8 b10 = *(const bf16x8*)(Ws + (16 + cl) * 1024 + ch0 * 8);
            bf16x8 b01 = *(const bf16x8*)(Ws + cl * 1024 + ch1 * 8);
            bf16x8 b11 = *(const bf16x8*)(Ws + (16 + cl) * 1024 + ch1 * 8);
            acc0a = __builtin_amdgcn_mfma_f32_16x16x32_bf16(a0.v, b00, acc0a, 0, 0, 0);
            acc1a = __builtin_amdgcn_mfma_f32_16x16x32_bf16(a0.v, b10, acc1a, 0, 0, 0);
            acc0b = __builtin_amdgcn_mfma_f32_16x16x32_bf16(a1.v, b01, acc0b, 0, 0, 0);
            acc1b = __builtin_amdgcn_mfma_f32_16x16x32_bf16(a1.v, b11, acc1b, 0, 0, 0);
        }
        f32x4 acc0 = acc0a + acc0b;
        f32x4 acc1 = acc1a + acc1b;
        // gate math: lane (q,cl<8) row-group q*4+r, col cc; zj/zo live in lane^8
        float zi[4], zj[4], zf[4], zo[4];
#pragma unroll
        for (int r = 0; r < 4; r++) {
            float a0 = acc0[r], a1 = acc1[r];
            float a0x = __shfl_xor(a0, 8);
            float a1x = __shfl_xor(a1, 8);
            zi[r] = a0; zj[r] = a0x; zf[r] = a1; zo[r] = a1x;
        }
        if (act) {
#pragma unroll
            for (int r = 0; r < 4; r++) {
                int m2 = wave * 16 + q * 4 + r;            // batch row
                float vi = zi[r] + pxi[r] + bi;
                float vj = zj[r] + pxj[r] + bj;
                float vf = zf[r] + pxf[r] + bfv + 1.0f;    // forget bias
                float vo = zo[r] + pxo[r] + bo;
                float cn = c[r] * sigmoidf_(vf) + sigmoidf_(vi) * tanhf_(vj);
                c[r] = cn;
                float h = tanhf_(cn) * sigmoidf_(vo);
                out[(size_t)(m2 * 128 + tt) * 1024 + n0 + cc] = h;
                st16cc(hnext + ((size_t)m2 * 1024 + n0 + cc) * 2, (uint32_t)f2bf(h));
            }
        }
        __syncthreads();   // vmcnt(0): h stores ACK'd at L3 before the signal
        if (t == 0) {
            __hip_atomic_fetch_add(&cnt[tt], 1, __ATOMIC_RELAXED, __HIP_MEMORY_SCOPE_AGENT);
        }
    }
}

// ---------------- launch ----------------
extern "C" void kernel_launch(void* const* d_in, const int* in_sizes, int n_in,
                              void* d_out, int out_size, void* d_ws, size_t ws_size,
                              hipStream_t stream) {
    const float* x = (const float*)d_in[0];
    const float* W = (const float*)d_in[1];
    const float* b = (const float*)d_in[2];
    float* out = (float*)d_out;
    char* ws = (char*)d_ws;

    // workspace layout (bytes):
    unsigned short* WXTH = (unsigned short*)(ws);                              // 8 MB
    unsigned short* WXTL = (unsigned short*)(ws + (size_t)8  * 1024 * 1024);   // 8 MB
    unsigned short* WHT  = (unsigned short*)(ws + (size_t)16 * 1024 * 1024);   // 8 MB
    float*          XZ   = (float*)         (ws + (size_t)24 * 1024 * 1024);   // 128 MB fp32
    unsigned short* HBUF = (unsigned short*)(ws + (size_t)152 * 1024 * 1024);  // 256 KB (2 bufs)
    int*            CNT  = (int*)(ws + (size_t)152 * 1024 * 1024 + 256 * 1024); // 512 B

    // zero h double-buffer + counters ((262144 + 512)/4 = 65664 words)
    k_init<<<256, 256, 0, stream>>>((uint32_t*)HBUF, 65664);
    dim3 gtw(64, 32);
    k_tw<<<gtw, 256, 0, stream>>>(W, WXTH, WXTL, WHT);
    dim3 gg(32, 64);   // x: N/128, y: M/128
    k_gemm1<<<gg, 256, 0, stream>>>(x, WXTH, WXTL, XZ);
    k_rnn<<<NB, 256, 0, stream>>>(XZ, WHT, b, HBUF, CNT, out);
}

// Round 6
// 1198.637 us; speedup vs baseline: 2.7416x; 1.3794x over previous
//
#include <hip/hip_runtime.h>
#include <stdint.h>

// Problem: B=64, T=128, F=1024, H=1024. x:[64,128,1024] f32, W:[2048,4096] f32, b:[4096] f32.
// out:[64,128,1024] f32.
#define BATCH 64
#define TSEQ  128
#define FDIM  1024
#define HDIM  1024
#define GDIM  4096              // 4H
#define MROWS 8192              // BATCH*TSEQ
#define NB    128               // persistent blocks in recurrent phase (co-resident on 256 CUs)

typedef short bf16x8 __attribute__((ext_vector_type(8)));   // 8 bf16 in 4 VGPRs
typedef float f32x4  __attribute__((ext_vector_type(4)));

__device__ __forceinline__ unsigned short f2bf(float f) {
    union { float f; uint32_t u; } v; v.f = f;
    uint32_t u = v.u;
    return (unsigned short)((u + 0x7FFFu + ((u >> 16) & 1u)) >> 16);  // RNE
}
__device__ __forceinline__ float bf2f(unsigned short h) {
    union { uint32_t u; float f; } v; v.u = ((uint32_t)h) << 16; return v.f;
}
__device__ __forceinline__ float sigmoidf_(float x) { return 1.f / (1.f + __expf(-x)); }
__device__ __forceinline__ float tanhf_(float x)    { return 2.f / (1.f + __expf(-2.f * x)) - 1.f; }

union SP { short s[8]; int4 v; };
union UU { int4 i; bf16x8 v; };

// L2-bypass 8B store (relaxed agent atomic -> global_store_dwordx2 sc0 sc1, lands at IF).
__device__ __forceinline__ void st64cc(void* p, unsigned long long v) {
    __hip_atomic_store((unsigned long long*)p, v, __ATOMIC_RELAXED, __HIP_MEMORY_SCOPE_AGENT);
}

// ---------------- init: zero cnt + h slot 0 ----------------
__global__ void k_init(uint32_t* p, int nwords) {
    int i = blockIdx.x * blockDim.x + threadIdx.x;
    int s = gridDim.x * blockDim.x;
    for (; i < nwords; i += s) p[i] = 0;
}

// ---------------- W fp32 [2048][4096] -> WxT hi/lo bf16 [4096][1024], WhT bf16 [4096][1024] ----
__global__ void k_tw(const float* __restrict__ W,
                     unsigned short* __restrict__ wxth, unsigned short* __restrict__ wxtl,
                     unsigned short* __restrict__ wht) {
    __shared__ float tile[64 * 65];
    const int nb = blockIdx.x;      // 0..63  (n tiles)
    const int kb = blockIdx.y;      // 0..31  (k tiles over 2048)
    const int t  = threadIdx.x;
    const int col = t & 63, rg = t >> 6;
#pragma unroll
    for (int i = 0; i < 16; i++) {
        int row = rg * 16 + i;
        tile[row * 65 + col] = W[(size_t)(kb * 64 + row) * 4096 + nb * 64 + col];
    }
    __syncthreads();
    if (kb < 16) {
        const int kbase = kb * 64;
#pragma unroll
        for (int i = 0; i < 16; i++) {
            int rp = rg * 16 + i;                      // n index within tile
            float v = tile[col * 65 + rp];             // = W[kb*64+col][nb*64+rp]
            unsigned short h = f2bf(v);
            size_t idx = (size_t)(nb * 64 + rp) * 1024 + kbase + col;
            wxth[idx] = h;
            wxtl[idx] = f2bf(v - bf2f(h));
        }
    } else {
        const int kbase = (kb - 16) * 64;
#pragma unroll
        for (int i = 0; i < 16; i++) {
            int rp = rg * 16 + i;
            float v = tile[col * 65 + rp];
            wht[(size_t)(nb * 64 + rp) * 1024 + kbase + col] = f2bf(v);
        }
    }
}

// ---------------- GEMM1: xz_f32[8192][4096] = x[8192][1024] @ Wx, split-bf16 (3-MFMA) ---------
__global__ __launch_bounds__(256) void k_gemm1(const float* __restrict__ Xf,
                                               const unsigned short* __restrict__ WxTh,
                                               const unsigned short* __restrict__ WxTl,
                                               float* __restrict__ xz) {
    __shared__ short Ash[128 * 40];   // stride 40 elems (80B) -> 2-way banks (free)
    __shared__ short Asl[128 * 40];
    __shared__ short Bsh[128 * 40];
    __shared__ short Bsl[128 * 40];
    const int n0 = blockIdx.x * 128;
    const int m0 = blockIdx.y * 128;
    const int t = threadIdx.x;
    const int wave = t >> 6, lane = t & 63;
    const int wm = wave >> 1, wn = wave & 1;
    const int q = lane >> 4, cl = lane & 15;
    const int row_a = t >> 2;            // 0..63
    const int kc = (t & 3) * 8;          // 8-elem chunk within the 32-elem k-slab

    f32x4 acc[4][4];
#pragma unroll
    for (int i = 0; i < 4; i++)
#pragma unroll
        for (int j = 0; j < 4; j++) acc[i][j] = (f32x4){0.f, 0.f, 0.f, 0.f};

    for (int kb = 0; kb < 32; kb++) {
        const int k0 = kb * 32;
        float va0[8], va1[8];
        {
            const float* p0 = Xf + (size_t)(m0 + row_a) * 1024 + k0 + kc;
            const float* p1 = Xf + (size_t)(m0 + 64 + row_a) * 1024 + k0 + kc;
            *(float4*)(va0)     = *(const float4*)(p0);
            *(float4*)(va0 + 4) = *(const float4*)(p0 + 4);
            *(float4*)(va1)     = *(const float4*)(p1);
            *(float4*)(va1 + 4) = *(const float4*)(p1 + 4);
        }
        int4 bh0 = *(const int4*)(WxTh + (size_t)(n0 + row_a)      * 1024 + k0 + kc);
        int4 bh1 = *(const int4*)(WxTh + (size_t)(n0 + 64 + row_a) * 1024 + k0 + kc);
        int4 bl0 = *(const int4*)(WxTl + (size_t)(n0 + row_a)      * 1024 + k0 + kc);
        int4 bl1 = *(const int4*)(WxTl + (size_t)(n0 + 64 + row_a) * 1024 + k0 + kc);
        __syncthreads();
        {
            SP h0, l0, h1, l1;
#pragma unroll
            for (int i = 0; i < 8; i++) {
                unsigned short h = f2bf(va0[i]);
                h0.s[i] = (short)h; l0.s[i] = (short)f2bf(va0[i] - bf2f(h));
                unsigned short g = f2bf(va1[i]);
                h1.s[i] = (short)g; l1.s[i] = (short)f2bf(va1[i] - bf2f(g));
            }
            *(int4*)(Ash + row_a * 40 + kc)        = h0.v;
            *(int4*)(Asl + row_a * 40 + kc)        = l0.v;
            *(int4*)(Ash + (64 + row_a) * 40 + kc) = h1.v;
            *(int4*)(Asl + (64 + row_a) * 40 + kc) = l1.v;
        }
        *(int4*)(Bsh + row_a * 40 + kc)        = bh0;
        *(int4*)(Bsh + (64 + row_a) * 40 + kc) = bh1;
        *(int4*)(Bsl + row_a * 40 + kc)        = bl0;
        *(int4*)(Bsl + (64 + row_a) * 40 + kc) = bl1;
        __syncthreads();
        bf16x8 ah[4], al[4], bh[4], bl[4];
#pragma unroll
        for (int i = 0; i < 4; i++) {
            ah[i] = *(const bf16x8*)(Ash + (wm * 64 + i * 16 + cl) * 40 + q * 8);
            al[i] = *(const bf16x8*)(Asl + (wm * 64 + i * 16 + cl) * 40 + q * 8);
        }
#pragma unroll
        for (int j = 0; j < 4; j++) {
            bh[j] = *(const bf16x8*)(Bsh + (wn * 64 + j * 16 + cl) * 40 + q * 8);
            bl[j] = *(const bf16x8*)(Bsl + (wn * 64 + j * 16 + cl) * 40 + q * 8);
        }
#pragma unroll
        for (int i = 0; i < 4; i++)
#pragma unroll
            for (int j = 0; j < 4; j++) {
                acc[i][j] = __builtin_amdgcn_mfma_f32_16x16x32_bf16(ah[i], bh[j], acc[i][j], 0, 0, 0);
                acc[i][j] = __builtin_amdgcn_mfma_f32_16x16x32_bf16(al[i], bh[j], acc[i][j], 0, 0, 0);
                acc[i][j] = __builtin_amdgcn_mfma_f32_16x16x32_bf16(ah[i], bl[j], acc[i][j], 0, 0, 0);
            }
    }
    // epilogue: C/D layout col=lane&15, row=q*4+reg; write fp32
#pragma unroll
    for (int i = 0; i < 4; i++) {
#pragma unroll
        for (int j = 0; j < 4; j++) {
            int gm = m0 + wm * 64 + i * 16 + q * 4;
            int gn = n0 + wn * 64 + j * 16 + cl;
#pragma unroll
            for (int r = 0; r < 4; r++)
                xz[(size_t)(gm + r) * 4096 + gn] = acc[i][j][r];
        }
    }
}

// ---------------- persistent recurrent kernel ----------------
// NB=128 blocks x 256 thr. Block owns 8 h-cols -> 32 gate cols [i(8) j(8) | f(8) o(8)].
// n0 swizzled so the 16 blocks of an XCD own 128 contiguous cols (full-line xz/h reuse in L2).
// h exchange: ROTATING buffer (write-once addresses) ->
//   producers: 8B L2-bypass stores (LDS-transposed rows), land at IF;
//   consumers: NORMAL cached dwordx4 loads — first block/XCD fills L2 from IF, 15 others hit L2.
//   No address reuse => no stale-L2 possible; no fences, no invalidates.
// signal: one relaxed fetch_add per block/step; t0 polls cnt[tt-1]==NB (relaxed, L2-bypass).
__global__ __launch_bounds__(256) void k_rnn(const float* __restrict__ xz,
                                             const unsigned short* __restrict__ WhT,
                                             const float* __restrict__ bias,
                                             unsigned short* hrot,       // 129 x [64][1024] bf16
                                             int* cnt,                   // TSEQ step counters
                                             float* __restrict__ out) {
    __shared__ short Ws[32 * 1024];     // 64 KB
    __shared__ short hs[64 * 8];        // h transpose staging, 1 KB
    const int t = threadIdx.x;
    const int blk = blockIdx.x;
    // XCD-grouped columns: blocks blk&7==x own cols [x*128, x*128+128)
    const int n0 = (((blk & 7) << 4) | (blk >> 3)) * 8;
    const int wave = t >> 6, lane = t & 63;
    const int q = lane >> 4, cl = lane & 15;
    const int m = wave * 16 + cl;       // A-fragment row (batch)

    // preload Wh slice into LDS: vcol = g*8+cc -> WhT row g*1024+n0+cc
    {
        const int vcol = t >> 3;            // 0..31
        const int part = t & 7;             // 0..7
        const int g = vcol >> 3, cc2 = vcol & 7, swl = vcol & 7;
        const unsigned short* src = WhT + (size_t)(g * 1024 + n0 + cc2) * 1024;
        short* dstrow = Ws + vcol * 1024;
#pragma unroll
        for (int i = 0; i < 16; i++) {
            int kch = part * 16 + i;        // 16B chunk id 0..127
            int4 v = *(const int4*)(src + kch * 8);
            *(int4*)(dstrow + ((kch ^ swl) * 8)) = v;
        }
    }
    const int cc = cl & 7;
    const bool act = (cl < 8);
    float bi = 0.f, bj = 0.f, bfv = 0.f, bo = 0.f;
    if (act) {
        bi  = bias[n0 + cc];
        bj  = bias[1024 + n0 + cc];
        bfv = bias[2048 + n0 + cc];
        bo  = bias[3072 + n0 + cc];
    }
    float c[4] = {0.f, 0.f, 0.f, 0.f};
    const int sw = cl & 7;
    __syncthreads();

    for (int tt = 0; tt < TSEQ; tt++) {
        // prefetch xz for this step (independent of other blocks' h) — hides latency under spin
        float pxi[4], pxj[4], pxf[4], pxo[4];
        if (act) {
#pragma unroll
            for (int r = 0; r < 4; r++) {
                int m2 = wave * 16 + q * 4 + r;
                const float* xp = xz + (size_t)(m2 * 128 + tt) * 4096 + n0 + cc;
                pxi[r] = xp[0];
                pxj[r] = xp[1024];
                pxf[r] = xp[2048];
                pxo[r] = xp[3072];
            }
        }
        if (tt > 0) {
            if (t == 0) {
                while (__hip_atomic_load(&cnt[tt - 1], __ATOMIC_RELAXED,
                                         __HIP_MEMORY_SCOPE_AGENT) < NB) { }
            }
            __syncthreads();
        }
        f32x4 acc0a = (f32x4){0.f, 0.f, 0.f, 0.f};
        f32x4 acc0b = (f32x4){0.f, 0.f, 0.f, 0.f};
        f32x4 acc1a = (f32x4){0.f, 0.f, 0.f, 0.f};
        f32x4 acc1b = (f32x4){0.f, 0.f, 0.f, 0.f};
        // cached reads of this step's h slot (write-once address -> no staleness)
        const char* ab = (const char*)hrot + (size_t)tt * 131072 + (size_t)m * 2048 + q * 16;
#pragma unroll 4
        for (int kb = 0; kb < 32; kb += 2) {
            UU a0, a1;
            a0.i = *(const int4*)(ab + kb * 64);
            a1.i = *(const int4*)(ab + kb * 64 + 64);
            const int ch0 = (kb * 4 + q) ^ sw;
            const int ch1 = ((kb + 1) * 4 + q) ^ sw;
            bf16x8 b00 = *(const bf16x8*)(Ws + cl * 1024 + ch0 * 8);
            bf16x8 b10 = *(const bf16x8*)(Ws + (16 + cl) * 1024 + ch0 * 8);
            bf16x8 b01 = *(const bf16x8*)(Ws + cl * 1024 + ch1 * 8);
            bf16x8 b11 = *(const bf16x8*)(Ws + (16 + cl) * 1024 + ch1 * 8);
            acc0a = __builtin_amdgcn_mfma_f32_16x16x32_bf16(a0.v, b00, acc0a, 0, 0, 0);
            acc1a = __builtin_amdgcn_mfma_f32_16x16x32_bf16(a0.v, b10, acc1a, 0, 0, 0);
            acc0b = __builtin_amdgcn_mfma_f32_16x16x32_bf16(a1.v, b01, acc0b, 0, 0, 0);
            acc1b = __builtin_amdgcn_mfma_f32_16x16x32_bf16(a1.v, b11, acc1b, 0, 0, 0);
        }
        f32x4 acc0 = acc0a + acc0b;
        f32x4 acc1 = acc1a + acc1b;
        // gate math: lane (q,cl<8) row-group q*4+r, col cc; zj/zo live in lane^8
        float zi[4], zj[4], zf[4], zo[4];
#pragma unroll
        for (int r = 0; r < 4; r++) {
            float a0 = acc0[r], a1 = acc1[r];
            float a0x = __shfl_xor(a0, 8);
            float a1x = __shfl_xor(a1, 8);
            zi[r] = a0; zj[r] = a0x; zf[r] = a1; zo[r] = a1x;
        }
        if (act) {
#pragma unroll
            for (int r = 0; r < 4; r++) {
                int m2 = wave * 16 + q * 4 + r;            // batch row
                float vi = zi[r] + pxi[r] + bi;
                float vj = zj[r] + pxj[r] + bj;
                float vf = zf[r] + pxf[r] + bfv + 1.0f;    // forget bias
                float vo = zo[r] + pxo[r] + bo;
                float cn = c[r] * sigmoidf_(vf) + sigmoidf_(vi) * tanhf_(vj);
                c[r] = cn;
                float h = tanhf_(cn) * sigmoidf_(vo);
                out[(size_t)(m2 * 128 + tt) * 1024 + n0 + cc] = h;
                hs[m2 * 8 + cc] = (short)f2bf(h);
            }
        }
        __syncthreads();   // hs visible to waves 0-1
        if (t < 128) {
            // row = t>>1 (0..63), half = t&1; 8B per store
            unsigned long long hv = *(const unsigned long long*)(hs + (t >> 1) * 8 + (t & 1) * 4);
            st64cc((char*)hrot + (size_t)(tt + 1) * 131072 + (size_t)(t >> 1) * 2048 + n0 * 2 + (t & 1) * 8, hv);
        }
        __syncthreads();   // vmcnt(0): h row-stores ACK'd at IF before signal
        if (t == 0) {
            __hip_atomic_fetch_add(&cnt[tt], 1, __ATOMIC_RELAXED, __HIP_MEMORY_SCOPE_AGENT);
        }
    }
}

// ---------------- launch ----------------
extern "C" void kernel_launch(void* const* d_in, const int* in_sizes, int n_in,
                              void* d_out, int out_size, void* d_ws, size_t ws_size,
                              hipStream_t stream) {
    const float* x = (const float*)d_in[0];
    const float* W = (const float*)d_in[1];
    const float* b = (const float*)d_in[2];
    float* out = (float*)d_out;
    char* ws = (char*)d_ws;

    // workspace layout (bytes):
    unsigned short* WXTH = (unsigned short*)(ws);                              // 8 MB
    unsigned short* WXTL = (unsigned short*)(ws + (size_t)8  * 1024 * 1024);   // 8 MB
    unsigned short* WHT  = (unsigned short*)(ws + (size_t)16 * 1024 * 1024);   // 8 MB
    float*          XZ   = (float*)         (ws + (size_t)24 * 1024 * 1024);   // 128 MB fp32
    int*            CNT  = (int*)           (ws + (size_t)152 * 1024 * 1024);  // 4 KB
    unsigned short* HROT = (unsigned short*)(ws + (size_t)152 * 1024 * 1024 + 4096); // 129*128KB

    // zero CNT (4 KB) + HROT slot 0 (128 KB) = 135168 B = 33792 words
    k_init<<<256, 256, 0, stream>>>((uint32_t*)CNT, 33792);
    dim3 gtw(64, 32);
    k_tw<<<gtw, 256, 0, stream>>>(W, WXTH, WXTL, WHT);
    dim3 gg(32, 64);   // x: N/128, y: M/128
    k_gemm1<<<gg, 256, 0, stream>>>(x, WXTH, WXTL, XZ);
    k_rnn<<<NB, 256, 0, stream>>>(XZ, WHT, b, HROT, CNT, out);
}